// Round 17
// baseline (1125.153 us; speedup 1.0000x reference)
//
#include <hip/hip_runtime.h>
#include <math.h>

#define BATCH 256
#define DIN 512
#define DFEAT 512
#define HSZ 512
#define VOCAB 32000
#define EMB 64
#define SLEN 16
#define NTILE 500          // VOCAB / 64 col-tiles (argmax view)
#define MARGIN 0.0625f

typedef __attribute__((ext_vector_type(8))) short bf16x8;
typedef __attribute__((ext_vector_type(4))) float f32x4;

__device__ inline unsigned bf16_rne(float x) {
    union { float f; unsigned u; } u; u.f = x;
    unsigned r = u.u + 0x7fff + ((u.u >> 16) & 1);
    return r >> 16;
}
__device__ inline void poll_ge(int* c, int target) {
    while (__hip_atomic_load(c, __ATOMIC_RELAXED, __HIP_MEMORY_SCOPE_AGENT) < target)
        __builtin_amdgcn_s_sleep(8);
}
__device__ inline void bump(int* c) {
    __hip_atomic_fetch_add(c, 1, __ATOMIC_RELEASE, __HIP_MEMORY_SCOPE_AGENT);
}
// coherent (sc1) agent-scope accessors for same-kernel cross-XCD data
__device__ inline float alf(const float* p) {
    return __hip_atomic_load(p, __ATOMIC_RELAXED, __HIP_MEMORY_SCOPE_AGENT);
}
__device__ inline unsigned alu(const unsigned* p) {
    return __hip_atomic_load(p, __ATOMIC_RELAXED, __HIP_MEMORY_SCOPE_AGENT);
}
__device__ inline void asf(float* p, float v) {
    __hip_atomic_store(p, v, __ATOMIC_RELAXED, __HIP_MEMORY_SCOPE_AGENT);
}
__device__ inline void asu(unsigned* p, unsigned v) {
    __hip_atomic_store(p, v, __ATOMIC_RELAXED, __HIP_MEMORY_SCOPE_AGENT);
}

// ---------- fp32 SMEM GEMM (prologue): C = A @ W^T (+bias) ----------
template<int BM, int BN, int BK, int TM, int TN>
__global__ __launch_bounds__(256) void gemm_atb(
    const float* __restrict__ A, const float* __restrict__ W,
    const float* __restrict__ bias, float* __restrict__ C, long long ldc,
    int M, int N, int K)
{
    __shared__ float As[BK][BM + 4];
    __shared__ float Bs[BK][BN + 4];
    constexpr int THREADS = (BM / TM) * (BN / TN);
    const int tid = threadIdx.x;
    const int tx = tid % (BN / TN);
    const int ty = tid / (BN / TN);
    const int row0 = blockIdx.y * BM;
    const int col0 = blockIdx.x * BN;
    float acc[TM][TN] = {};
    for (int k0 = 0; k0 < K; k0 += BK) {
        for (int i = tid; i < BM * BK; i += THREADS) {
            int m = i / BK, k = i % BK;
            As[k][m] = A[(long long)(row0 + m) * K + k0 + k];
        }
        for (int i = tid; i < BN * BK; i += THREADS) {
            int n = i / BK, k = i % BK;
            Bs[k][n] = W[(long long)(col0 + n) * K + k0 + k];
        }
        __syncthreads();
        #pragma unroll
        for (int kk = 0; kk < BK; ++kk) {
            float a[TM], b[TN];
            #pragma unroll
            for (int i = 0; i < TM; ++i) a[i] = As[kk][ty * TM + i];
            #pragma unroll
            for (int j = 0; j < TN; ++j) b[j] = Bs[kk][tx * TN + j];
            #pragma unroll
            for (int i = 0; i < TM; ++i)
                #pragma unroll
                for (int j = 0; j < TN; ++j)
                    acc[i][j] = fmaf(a[i], b[j], acc[i][j]);
        }
        __syncthreads();
    }
    #pragma unroll
    for (int i = 0; i < TM; ++i) {
        long long m = row0 + ty * TM + i;
        float* crow = C + m * ldc;
        #pragma unroll
        for (int j = 0; j < TN; ++j) {
            int n = col0 + tx * TN + j;
            float v = acc[i][j];
            if (bias) v += bias[n];
            crow[n] = v;
        }
    }
}

// ---------- prologue: Wb cast, Wcat2/bcat2 build, counter reset ----------
__global__ void prep_kernel(const float* __restrict__ out_W, ushort* __restrict__ Wb,
                            const float* __restrict__ W_ih, const float* __restrict__ W_hh,
                            const float* __restrict__ b_ih, const float* __restrict__ b_hh,
                            float* __restrict__ Wcat2, float* __restrict__ bcat2,
                            int* __restrict__ done)
{
    const int stride = gridDim.x * 256;
    const int t0 = blockIdx.x * 256 + threadIdx.x;
    for (int i = t0; i < VOCAB * HSZ / 4; i += stride) {
        const float4 v = ((const float4*)out_W)[i];
        ushort4 o;
        o.x = (ushort)bf16_rne(v.x); o.y = (ushort)bf16_rne(v.y);
        o.z = (ushort)bf16_rne(v.z); o.w = (ushort)bf16_rne(v.w);
        ((ushort4*)Wb)[i] = o;
    }
    for (long long i = t0; i < 2048LL * 576; i += stride) {
        int g = (int)(i / 576), k = (int)(i % 576);
        int j = g >> 2, comp = g & 3;
        float v;
        if (comp == 0)      v = (k < 64) ? W_ih[j * 64 + k]          : W_hh[(long long)j * 512 + k - 64];
        else if (comp == 1) v = (k < 64) ? W_ih[(512 + j) * 64 + k]  : W_hh[(long long)(512 + j) * 512 + k - 64];
        else if (comp == 2) v = (k < 64) ? W_ih[(1024 + j) * 64 + k] : 0.f;
        else                v = (k < 64) ? 0.f                        : W_hh[(long long)(1024 + j) * 512 + k - 64];
        Wcat2[i] = v;
    }
    for (int i = t0; i < 2048; i += stride) {
        int j = i >> 2, comp = i & 3;
        float bv = (comp == 0) ? b_ih[j] + b_hh[j]
                 : (comp == 1) ? b_ih[512 + j] + b_hh[512 + j]
                 : (comp == 2) ? b_ih[1024 + j] : b_hh[1024 + j];
        bcat2[i] = bv;
    }
    for (int i = t0; i < 256; i += stride) done[i] = 0;
}

// ================= fallback bodies (R14/R16-validated, plain loads) =================
__device__ __forceinline__ int argmax_body(int b, int tprev,
    const float* __restrict__ tmaxv, const float* __restrict__ lprev,
    const float* __restrict__ href, const float* __restrict__ out_W,
    const float* __restrict__ out_b, float* __restrict__ seq, char* sm)
{
    float* s_red = (float*)sm;
    int*   s_qt  = (int*)(sm + 1024);
    int*   s_cand= (int*)(sm + 1280);
    float* s_rv  = (float*)(sm + 1536);
    int*   s_cnt = (int*)(sm + 1792);
    int*   s_sym = (int*)(sm + 1800);
    const int tid = threadIdx.x;
    const int lane = tid & 63, wave = tid >> 6;
    const float* row = lprev + (long long)b * (SLEN * (long long)VOCAB);

    float v0 = tmaxv[(long long)b * 512 + tid];
    float v1 = (tid + 256 < NTILE) ? tmaxv[(long long)b * 512 + 256 + tid] : -INFINITY;
    s_red[tid] = fmaxf(v0, v1); __syncthreads();
    for (int s = 128; s > 0; s >>= 1) {
        if (tid < s) s_red[tid] = fmaxf(s_red[tid], s_red[tid + s]);
        __syncthreads();
    }
    float M = s_red[0];
    if (tid == 0) { s_cnt[0] = 0; s_cnt[1] = 0; }
    __syncthreads();
    if (v0 >= M - MARGIN) { int s = atomicAdd(&s_cnt[0], 1); if (s < 64) s_qt[s] = tid; }
    if (v1 >= M - MARGIN) { int s = atomicAdd(&s_cnt[0], 1); if (s < 64) s_qt[s] = tid + 256; }
    __syncthreads();
    int nq = min(s_cnt[0], 64);
    for (int idx = tid; idx < nq * 64; idx += 256) {
        int c = s_qt[idx >> 6] * 64 + (idx & 63);
        if (row[c] >= M - MARGIN) {
            int s = atomicAdd(&s_cnt[1], 1);
            if (s < 64) s_cand[s] = c;
        }
    }
    __syncthreads();
    int nc = min(s_cnt[1], 64);
    const float* hrow = href + (long long)b * 512;
    for (int ci = wave; ci < nc; ci += 4) {
        int vv = s_cand[ci];
        const float* wrow = out_W + (long long)vv * 512;
        float s = 0.f;
        for (int k = lane; k < 512; k += 64) s = fmaf(hrow[k], wrow[k], s);
        for (int off = 32; off > 0; off >>= 1) s += __shfl_down(s, off, 64);
        if (lane == 0) s_rv[ci] = s + out_b[vv];
    }
    __syncthreads();
    if (tid == 0) {
        float bv = -INFINITY; int sym = 0x7fffffff;
        for (int ci = 0; ci < nc; ++ci) {
            float xx = s_rv[ci]; int c = s_cand[ci];
            if (xx > bv || (xx == bv && c < sym)) { bv = xx; sym = c; }
        }
        if (sym < 0 || sym >= VOCAB) sym = 0;
        seq[b * SLEN + tprev] = (float)sym;
        *s_sym = sym;
    }
    __syncthreads();
    return *s_sym;
}

template<bool FIRST>
__device__ __forceinline__ void gru_body_fb(int blk,
    const float* __restrict__ hprev, float* __restrict__ hnew,
    const float* __restrict__ Wcat2, const float* __restrict__ bcat2,
    const float* __restrict__ ebuf, const float* __restrict__ sos,
    unsigned* __restrict__ hbfu, int* __restrict__ done, int wt_e, char* sm)
{
    const int tid = threadIdx.x;
    const int ty = blk >> 5;
    const int tx = blk & 31;
    float* As = (float*)sm;
    float* Bs = (float*)(sm + 4608);
    const int tyt = tid >> 4;
    const int txt = tid & 15;
    float acc[4] = {};

    for (int k0 = 64; k0 < 576; k0 += 64) {
        for (int i = tid; i < 16 * 64; i += 256) {
            int m = i >> 6, k = i & 63;
            As[k * 18 + m] = hprev[(long long)(ty * 16 + m) * 512 + (k0 - 64) + k];
        }
        for (int i = tid; i < 64 * 64; i += 256) {
            int n = i >> 6, k = i & 63;
            Bs[k * 68 + n] = Wcat2[(long long)(tx * 64 + n) * 576 + k0 + k];
        }
        __syncthreads();
        #pragma unroll 8
        for (int kk = 0; kk < 64; ++kk) {
            const float a = As[kk * 18 + tyt];
            const float4 b = *(const float4*)&Bs[kk * 68 + txt * 4];
            acc[0] = fmaf(a, b.x, acc[0]);
            acc[1] = fmaf(a, b.y, acc[1]);
            acc[2] = fmaf(a, b.z, acc[2]);
            acc[3] = fmaf(a, b.w, acc[3]);
        }
        __syncthreads();
    }
    if (!FIRST) {
        if (tid == 0) poll_ge(done, wt_e);
        __syncthreads();
    }
    {
        for (int i = tid; i < 16 * 64; i += 256) {
            int m = i >> 6, k = i & 63;
            As[k * 18 + m] = FIRST ? sos[k] : ebuf[(long long)(ty * 16 + m) * EMB + k];
        }
        for (int i = tid; i < 64 * 64; i += 256) {
            int n = i >> 6, k = i & 63;
            Bs[k * 68 + n] = Wcat2[(long long)(tx * 64 + n) * 576 + k];
        }
        __syncthreads();
        #pragma unroll 8
        for (int kk = 0; kk < 64; ++kk) {
            const float a = As[kk * 18 + tyt];
            const float4 b = *(const float4*)&Bs[kk * 68 + txt * 4];
            acc[0] = fmaf(a, b.x, acc[0]);
            acc[1] = fmaf(a, b.y, acc[1]);
            acc[2] = fmaf(a, b.z, acc[2]);
            acc[3] = fmaf(a, b.w, acc[3]);
        }
        __syncthreads();
    }
    float* gt = (float*)sm;
    ushort* sh_hb = (ushort*)(sm + 8192);
    #pragma unroll
    for (int j = 0; j < 4; ++j)
        gt[tyt * 64 + txt * 4 + j] = acc[j];
    __syncthreads();
    {
        int row = tid >> 4, jl = tid & 15;
        int jg = tx * 16 + jl;
        float gr  = gt[row * 64 + jl * 4 + 0] + bcat2[jg * 4 + 0];
        float gz  = gt[row * 64 + jl * 4 + 1] + bcat2[jg * 4 + 1];
        float gni = gt[row * 64 + jl * 4 + 2] + bcat2[jg * 4 + 2];
        float gnh = gt[row * 64 + jl * 4 + 3] + bcat2[jg * 4 + 3];
        float r = 1.0f / (1.0f + expf(-gr));
        float z = 1.0f / (1.0f + expf(-gz));
        float n = tanhf(gni + r * gnh);
        long long bglob = ty * 16 + row;
        float hold = hprev[bglob * 512 + jg];
        float h = (1.0f - z) * n + z * hold;
        hnew[bglob * 512 + jg] = h;
        sh_hb[row * 16 + jl] = (ushort)bf16_rne(h);
    }
    __syncthreads();
    if (tid < 128) {
        int row = tid >> 3, jp = tid & 7;
        unsigned lo = sh_hb[row * 16 + jp * 2];
        unsigned hi = sh_hb[row * 16 + jp * 2 + 1];
        hbfu[(long long)(ty * 16 + row) * 256 + tx * 8 + jp] = (hi << 16) | lo;
    }
}

__device__ __forceinline__ void logits_body_fb(int bid,
    const ushort* __restrict__ hbf, const ushort* __restrict__ Wb,
    const float* __restrict__ out_b, float* __restrict__ lbase,
    float* __restrict__ tmaxv, char* sm)
{
    char* As = sm;
    char* Bs = sm + 16384;
    float* s_mv = (float*)(sm + 24576);
    const int tid = threadIdx.x;
    const int lane = tid & 63;
    const int wave = tid >> 6;
    const int job = (bid & 7) * 125 + (bid >> 3);
    const int jx = job >> 1;
    const int jy = job & 1;
    const int row0 = jy * 128;
    const int col0 = jx * 64;

    f32x4 acc[2][4] = {};
    const int srow = tid >> 3;
    const int sch = tid & 7;

    for (int k0 = 0; k0 < 512; k0 += 64) {
        #pragma unroll
        for (int ra = 0; ra < 4; ++ra) {
            int row = ra * 32 + srow;
            const char* g = (const char*)(hbf + (long long)(row0 + row) * 512 + k0) + ((sch ^ (row & 7)) * 16);
            __builtin_amdgcn_global_load_lds(
                (const __attribute__((address_space(1))) void*)g,
                (__attribute__((address_space(3))) void*)(As + row * 128 + sch * 16), 16, 0, 0);
        }
        #pragma unroll
        for (int rb = 0; rb < 2; ++rb) {
            int row = rb * 32 + srow;
            const char* g = (const char*)(Wb + (long long)(col0 + row) * 512 + k0) + ((sch ^ (row & 7)) * 16);
            __builtin_amdgcn_global_load_lds(
                (const __attribute__((address_space(1))) void*)g,
                (__attribute__((address_space(3))) void*)(Bs + row * 128 + sch * 16), 16, 0, 0);
        }
        __syncthreads();
        #pragma unroll
        for (int k32 = 0; k32 < 64; k32 += 32) {
            bf16x8 af[2], bfr[4];
            #pragma unroll
            for (int f = 0; f < 2; ++f) {
                int rA = wave * 32 + f * 16 + (lane & 15);
                int byteA = (rA * 128 + (k32 + ((lane >> 4) << 3)) * 2) ^ ((rA & 7) << 4);
                af[f] = *(const bf16x8*)&As[byteA];
            }
            #pragma unroll
            for (int j = 0; j < 4; ++j) {
                int rB = j * 16 + (lane & 15);
                int byteB = (rB * 128 + (k32 + ((lane >> 4) << 3)) * 2) ^ ((rB & 7) << 4);
                bfr[j] = *(const bf16x8*)&Bs[byteB];
            }
            #pragma unroll
            for (int f = 0; f < 2; ++f)
                #pragma unroll
                for (int j = 0; j < 4; ++j)
                    acc[f][j] = __builtin_amdgcn_mfma_f32_16x16x32_bf16(af[f], bfr[j], acc[f][j], 0, 0, 0);
        }
        __syncthreads();
    }
    #pragma unroll
    for (int f = 0; f < 2; ++f) {
        #pragma unroll
        for (int q = 0; q < 4; ++q) {
            int r_local = wave * 32 + f * 16 + ((lane >> 4) << 2) + q;
            float* crow = lbase + (long long)(row0 + r_local) * (SLEN * (long long)VOCAB);
            float mv = -INFINITY;
            #pragma unroll
            for (int j = 0; j < 4; ++j) {
                int c = col0 + j * 16 + (lane & 15);
                float v = acc[f][j][q] + out_b[c];
                __builtin_nontemporal_store(v, &crow[c]);
                mv = fmaxf(mv, v);
            }
            #pragma unroll
            for (int m = 1; m < 16; m <<= 1) mv = fmaxf(mv, __shfl_xor(mv, m, 64));
            if ((lane & 15) == 0) s_mv[r_local] = mv;
        }
    }
    __syncthreads();
    if (tid < 128)
        tmaxv[(long long)(row0 + tid) * 512 + jx] = s_mv[tid];
}

// ================= persistent (coherent, sc1) bodies =================
__device__ __forceinline__ int argmax_body_p(int b, int tprev,
    const float* tmaxv, const float* lprev, const float* href,
    const float* __restrict__ out_W, const float* __restrict__ out_b,
    float* __restrict__ seq, char* sm)
{
    float* s_red = (float*)sm;
    int*   s_qt  = (int*)(sm + 1024);
    int*   s_cand= (int*)(sm + 1280);
    float* s_rv  = (float*)(sm + 1536);
    int*   s_cnt = (int*)(sm + 1792);
    int*   s_sym = (int*)(sm + 1800);
    const int tid = threadIdx.x;
    const int lane = tid & 63, wave = tid >> 6;
    const float* row = lprev + (long long)b * (SLEN * (long long)VOCAB);

    float v0 = alf(&tmaxv[(long long)b * 512 + tid]);
    float v1 = (tid + 256 < NTILE) ? alf(&tmaxv[(long long)b * 512 + 256 + tid]) : -INFINITY;
    s_red[tid] = fmaxf(v0, v1); __syncthreads();
    for (int s = 128; s > 0; s >>= 1) {
        if (tid < s) s_red[tid] = fmaxf(s_red[tid], s_red[tid + s]);
        __syncthreads();
    }
    float M = s_red[0];
    if (tid == 0) { s_cnt[0] = 0; s_cnt[1] = 0; }
    __syncthreads();
    if (v0 >= M - MARGIN) { int s = atomicAdd(&s_cnt[0], 1); if (s < 64) s_qt[s] = tid; }
    if (v1 >= M - MARGIN) { int s = atomicAdd(&s_cnt[0], 1); if (s < 64) s_qt[s] = tid + 256; }
    __syncthreads();
    int nq = min(s_cnt[0], 64);
    for (int idx = tid; idx < nq * 64; idx += 256) {
        int c = s_qt[idx >> 6] * 64 + (idx & 63);
        if (alf(&row[c]) >= M - MARGIN) {
            int s = atomicAdd(&s_cnt[1], 1);
            if (s < 64) s_cand[s] = c;
        }
    }
    __syncthreads();
    int nc = min(s_cnt[1], 64);
    const float* hrow = href + (long long)b * 512;
    for (int ci = wave; ci < nc; ci += 4) {
        int vv = s_cand[ci];
        const float* wrow = out_W + (long long)vv * 512;
        float s = 0.f;
        for (int k = lane; k < 512; k += 64) s = fmaf(alf(&hrow[k]), wrow[k], s);
        for (int off = 32; off > 0; off >>= 1) s += __shfl_down(s, off, 64);
        if (lane == 0) s_rv[ci] = s + out_b[vv];
    }
    __syncthreads();
    if (tid == 0) {
        float bv = -INFINITY; int sym = 0x7fffffff;
        for (int ci = 0; ci < nc; ++ci) {
            float xx = s_rv[ci]; int c = s_cand[ci];
            if (xx > bv || (xx == bv && c < sym)) { bv = xx; sym = c; }
        }
        if (sym < 0 || sym >= VOCAB) sym = 0;
        seq[b * SLEN + tprev] = (float)sym;
        *s_sym = sym;
    }
    __syncthreads();
    return *s_sym;
}

__device__ __forceinline__ void gru_body_p(int g, int t,
    const float* hprev, float* hnew,
    const float* __restrict__ Wcat2, const float* __restrict__ bcat2,
    const float* ebuf, const float* __restrict__ sos,
    unsigned* hbfu, int* done, char* sm)
{
    const int tid = threadIdx.x;
    const int ty = g >> 5;
    const int tx = g & 31;
    float* As = (float*)sm;
    float* Bs = (float*)(sm + 4608);
    const int tyt = tid >> 4;
    const int txt = tid & 15;
    float acc[4] = {};

    if (t > 0) {   // wait for h(t) half written by G(t-1)
        if (tid == 0) poll_ge(done + (t - 1) * 8 + 1 + (ty >= 8 ? 1 : 0), 256);
        __syncthreads();
    }
    for (int k0 = 64; k0 < 576; k0 += 64) {
        for (int i = tid; i < 16 * 64; i += 256) {
            int m = i >> 6, k = i & 63;
            As[k * 18 + m] = alf(&hprev[(long long)(ty * 16 + m) * 512 + (k0 - 64) + k]);
        }
        for (int i = tid; i < 64 * 64; i += 256) {
            int n = i >> 6, k = i & 63;
            Bs[k * 68 + n] = Wcat2[(long long)(tx * 64 + n) * 576 + k0 + k];
        }
        __syncthreads();
        #pragma unroll 8
        for (int kk = 0; kk < 64; ++kk) {
            const float a = As[kk * 18 + tyt];
            const float4 b = *(const float4*)&Bs[kk * 68 + txt * 4];
            acc[0] = fmaf(a, b.x, acc[0]);
            acc[1] = fmaf(a, b.y, acc[1]);
            acc[2] = fmaf(a, b.z, acc[2]);
            acc[3] = fmaf(a, b.w, acc[3]);
        }
        __syncthreads();
    }
    if (t > 0) {   // wait for all A(t)
        if (tid == 0) poll_ge(done + t * 8 + 0, 256);
        __syncthreads();
    }
    {
        for (int i = tid; i < 16 * 64; i += 256) {
            int m = i >> 6, k = i & 63;
            As[k * 18 + m] = (t == 0) ? sos[k] : alf(&ebuf[(long long)(ty * 16 + m) * EMB + k]);
        }
        for (int i = tid; i < 64 * 64; i += 256) {
            int n = i >> 6, k = i & 63;
            Bs[k * 68 + n] = Wcat2[(long long)(tx * 64 + n) * 576 + k];
        }
        __syncthreads();
        #pragma unroll 8
        for (int kk = 0; kk < 64; ++kk) {
            const float a = As[kk * 18 + tyt];
            const float4 b = *(const float4*)&Bs[kk * 68 + txt * 4];
            acc[0] = fmaf(a, b.x, acc[0]);
            acc[1] = fmaf(a, b.y, acc[1]);
            acc[2] = fmaf(a, b.z, acc[2]);
            acc[3] = fmaf(a, b.w, acc[3]);
        }
        __syncthreads();
    }
    float* gt = (float*)sm;
    ushort* sh_hb = (ushort*)(sm + 8192);
    #pragma unroll
    for (int j = 0; j < 4; ++j)
        gt[tyt * 64 + txt * 4 + j] = acc[j];
    __syncthreads();
    {
        int row = tid >> 4, jl = tid & 15;
        int jg = tx * 16 + jl;
        float gr  = gt[row * 64 + jl * 4 + 0] + bcat2[jg * 4 + 0];
        float gz  = gt[row * 64 + jl * 4 + 1] + bcat2[jg * 4 + 1];
        float gni = gt[row * 64 + jl * 4 + 2] + bcat2[jg * 4 + 2];
        float gnh = gt[row * 64 + jl * 4 + 3] + bcat2[jg * 4 + 3];
        float r = 1.0f / (1.0f + expf(-gr));
        float z = 1.0f / (1.0f + expf(-gz));
        float n = tanhf(gni + r * gnh);
        long long bglob = ty * 16 + row;
        float hold = alf(&hprev[bglob * 512 + jg]);
        float h = (1.0f - z) * n + z * hold;
        asf(&hnew[bglob * 512 + jg], h);
        sh_hb[row * 16 + jl] = (ushort)bf16_rne(h);
    }
    __syncthreads();
    if (tid < 128) {
        int row = tid >> 3, jp = tid & 7;
        unsigned lo = sh_hb[row * 16 + jp * 2];
        unsigned hi = sh_hb[row * 16 + jp * 2 + 1];
        asu(&hbfu[(long long)(ty * 16 + row) * 256 + tx * 8 + jp], (hi << 16) | lo);
    }
    __syncthreads();
    if (tid == 0) bump(done + t * 8 + 1 + (ty >= 8 ? 1 : 0));
    __syncthreads();
}

__device__ __forceinline__ void logits_body_p(int jid, int t,
    const unsigned* hbfu, const ushort* __restrict__ Wb,
    const float* __restrict__ out_b, float* lbase,
    float* tmaxv, int* done, char* sm)
{
    char* As = sm;
    char* Bs = sm + 16384;
    float* s_mv = (float*)(sm + 24576);
    const int tid = threadIdx.x;
    const int lane = tid & 63;
    const int wave = tid >> 6;
    const int job = (jid & 7) * 125 + (jid >> 3);
    const int jx = job >> 1;
    const int jy = job & 1;
    const int row0 = jy * 128;
    const int col0 = jx * 64;

    if (tid == 0) poll_ge(done + t * 8 + 1 + jy, 256);
    __syncthreads();

    f32x4 acc[2][4] = {};
    const int srow = tid >> 3;
    const int sch = tid & 7;

    for (int k0 = 0; k0 < 512; k0 += 64) {
        // A-panel: manual coherent staging (sc1 loads + ds_write), same swizzle
        #pragma unroll
        for (int ra = 0; ra < 4; ++ra) {
            int row = ra * 32 + srow;
            long long u = (long long)(row0 + row) * 256 + (k0 >> 1) + ((sch ^ (row & 7)) << 2);
            uint4 vv;
            vv.x = alu(&hbfu[u]);
            vv.y = alu(&hbfu[u + 1]);
            vv.z = alu(&hbfu[u + 2]);
            vv.w = alu(&hbfu[u + 3]);
            *(uint4*)(As + row * 128 + sch * 16) = vv;
        }
        #pragma unroll
        for (int rb = 0; rb < 2; ++rb) {
            int row = rb * 32 + srow;
            const char* g = (const char*)(Wb + (long long)(col0 + row) * 512 + k0) + ((sch ^ (row & 7)) * 16);
            __builtin_amdgcn_global_load_lds(
                (const __attribute__((address_space(1))) void*)g,
                (__attribute__((address_space(3))) void*)(Bs + row * 128 + sch * 16), 16, 0, 0);
        }
        __syncthreads();
        #pragma unroll
        for (int k32 = 0; k32 < 64; k32 += 32) {
            bf16x8 af[2], bfr[4];
            #pragma unroll
            for (int f = 0; f < 2; ++f) {
                int rA = wave * 32 + f * 16 + (lane & 15);
                int byteA = (rA * 128 + (k32 + ((lane >> 4) << 3)) * 2) ^ ((rA & 7) << 4);
                af[f] = *(const bf16x8*)&As[byteA];
            }
            #pragma unroll
            for (int j = 0; j < 4; ++j) {
                int rB = j * 16 + (lane & 15);
                int byteB = (rB * 128 + (k32 + ((lane >> 4) << 3)) * 2) ^ ((rB & 7) << 4);
                bfr[j] = *(const bf16x8*)&Bs[byteB];
            }
            #pragma unroll
            for (int f = 0; f < 2; ++f)
                #pragma unroll
                for (int j = 0; j < 4; ++j)
                    acc[f][j] = __builtin_amdgcn_mfma_f32_16x16x32_bf16(af[f], bfr[j], acc[f][j], 0, 0, 0);
        }
        __syncthreads();
    }
    #pragma unroll
    for (int f = 0; f < 2; ++f) {
        #pragma unroll
        for (int q = 0; q < 4; ++q) {
            int r_local = wave * 32 + f * 16 + ((lane >> 4) << 2) + q;
            float* crow = lbase + (long long)(row0 + r_local) * (SLEN * (long long)VOCAB);
            float mv = -INFINITY;
            #pragma unroll
            for (int j = 0; j < 4; ++j) {
                int c = col0 + j * 16 + (lane & 15);
                float v = acc[f][j][q] + out_b[c];
                asf(&crow[c], v);
                mv = fmaxf(mv, v);
            }
            #pragma unroll
            for (int m = 1; m < 16; m <<= 1) mv = fmaxf(mv, __shfl_xor(mv, m, 64));
            if ((lane & 15) == 0) s_mv[r_local] = mv;
        }
    }
    __syncthreads();
    if (tid < 128)
        asf(&tmaxv[(long long)(row0 + tid) * 512 + jx], s_mv[tid]);
    __syncthreads();
    if (tid == 0) bump(done + t * 8 + 3 + jy);
    __syncthreads();
}

// ================= persistent kernel: grid-stride workers over A/G/L jobs =================
__global__ __launch_bounds__(256) void persist_kernel(
    float* hring,                        // 4 slots of [B][H]
    const float* __restrict__ Wcat2, const float* __restrict__ bcat2,
    float* ering,                        // 2 slots of [B][E]
    const float* __restrict__ sos,
    unsigned* huring,                    // 4 slots of [B][256] u32
    const ushort* __restrict__ Wb,
    const float* __restrict__ out_W, const float* __restrict__ out_b,
    const float* __restrict__ emb, float* __restrict__ seq,
    float* tmring,                       // 2 slots of [B][512]
    float* logits, int* done)
{
    __shared__ __align__(16) char smem[25600];
    const int tid = threadIdx.x;
    const int P = gridDim.x;

    for (int t = 0; t <= SLEN; ++t) {
        float* h_t  = hring + (size_t)(t & 3) * BATCH * HSZ;
        // ---- A phase: argmax of step t-1, fill ebuf(t) ----
        if (t > 0) {
            float* tm_p = tmring + (size_t)((t - 1) & 1) * BATCH * 512;
            const float* lprev = logits + (long long)(t - 1) * VOCAB;
            float* eb_t = ering + (size_t)(t & 1) * BATCH * EMB;
            for (int b = blockIdx.x; b < BATCH; b += P) {
                if (tid == 0) poll_ge(done + (t - 1) * 8 + 3 + (b >= 128 ? 1 : 0), 500);
                __syncthreads();
                int sym = argmax_body_p(b, t - 1, tm_p, lprev, h_t, out_W, out_b, seq, smem);
                if (t < SLEN) {
                    if (tid < EMB)
                        asf(&eb_t[(long long)b * EMB + tid], emb[(long long)sym * EMB + tid]);
                    __syncthreads();
                    if (tid == 0) bump(done + t * 8 + 0);
                }
                __syncthreads();
            }
        }
        if (t == SLEN) break;

        // ---- G phase ----
        {
            float* h_t1 = hring + (size_t)((t + 1) & 3) * BATCH * HSZ;
            float* eb_t = ering + (size_t)(t & 1) * BATCH * EMB;
            unsigned* hu_t = huring + (size_t)(t & 3) * BATCH * 256;
            for (int g = blockIdx.x; g < 512; g += P)
                gru_body_p(g, t, h_t, h_t1, Wcat2, bcat2, eb_t, sos, hu_t, done, smem);
        }
        // ---- L phase ----
        {
            unsigned* hu_t = huring + (size_t)(t & 3) * BATCH * 256;
            float* tm_t = tmring + (size_t)(t & 1) * BATCH * 512;
            float* lbase = logits + (long long)t * VOCAB;
            for (int l = blockIdx.x; l < 1000; l += P)
                logits_body_p(l, t, hu_t, Wb, out_b, lbase, tm_t, done, smem);
        }
    }
}

// ================= fallback kernels (R14/R16-validated two-node path) =================
template<bool FIRST>
__global__ __launch_bounds__(256) void ag2_kernel(
    const float* __restrict__ hprev, float* __restrict__ hnew,
    const float* __restrict__ Wcat2, const float* __restrict__ bcat2,
    float* __restrict__ ebuf, const float* __restrict__ sos,
    unsigned* __restrict__ hbfu,
    const float* __restrict__ tmaxv, const float* __restrict__ lprev,
    const float* __restrict__ out_W, const float* __restrict__ out_b,
    const float* __restrict__ emb, float* __restrict__ seq,
    int* __restrict__ done, int wt_e, int tprev)
{
    __shared__ __align__(16) char smem[25600];
    const int tid = threadIdx.x;
    const int bid = blockIdx.x;
    if (!FIRST && bid < BATCH) {
        int sym = argmax_body(bid, tprev, tmaxv, lprev, hprev, out_W, out_b, seq, smem);
        if (tid < EMB)
            asf(&ebuf[(long long)bid * EMB + tid], emb[(long long)sym * EMB + tid]);
        __syncthreads();
        if (tid == 0) bump(done);
        __syncthreads();
    }
    gru_body_fb<FIRST>(bid, hprev, hnew, Wcat2, bcat2, ebuf, sos, hbfu, done, wt_e, smem);
}

__global__ __launch_bounds__(256) void logits_bm128_kernel(
    const ushort* __restrict__ hbf, const ushort* __restrict__ Wb,
    const float* __restrict__ out_b,
    float* __restrict__ lbase, float* __restrict__ tmaxv)
{
    __shared__ __align__(16) char smem[25600];
    logits_body_fb(blockIdx.x, hbf, Wb, out_b, lbase, tmaxv, smem);
}

__global__ __launch_bounds__(256) void argmax_final(
    const float* __restrict__ tmaxv, const float* __restrict__ lbase,
    const float* __restrict__ h, const float* __restrict__ out_W,
    const float* __restrict__ out_b, float* __restrict__ seq, int t)
{
    __shared__ __align__(16) char smem[2048];
    argmax_body(blockIdx.x, t, tmaxv, lbase, h, out_W, out_b, seq, smem);
}

extern "C" void kernel_launch(void* const* d_in, const int* in_sizes, int n_in,
                              void* d_out, int out_size, void* d_ws, size_t ws_size,
                              hipStream_t stream) {
    const float* x     = (const float*)d_in[0];
    const float* enc_W = (const float*)d_in[1];
    const float* enc_b = (const float*)d_in[2];
    const float* in_W  = (const float*)d_in[3];
    const float* in_b  = (const float*)d_in[4];
    const float* W_ih  = (const float*)d_in[5];
    const float* W_hh  = (const float*)d_in[6];
    const float* b_ih  = (const float*)d_in[7];
    const float* b_hh  = (const float*)d_in[8];
    const float* out_W = (const float*)d_in[9];
    const float* out_b = (const float*)d_in[10];
    const float* emb   = (const float*)d_in[11];
    const float* sos   = (const float*)d_in[12];

    float* seq    = (float*)d_out;
    float* logits = (float*)d_out + BATCH * SLEN;

    // shared prefix
    char* p = (char*)d_ws;
    ushort* Wb    = (ushort*)p;   p += (size_t)VOCAB * HSZ * 2;
    float* Wcat2  = (float*)p;    p += (size_t)2048 * 576 * 4;
    float* bcat2  = (float*)p;    p += 2048 * 4;
    float* feat   = (float*)p;    p += (size_t)BATCH * DFEAT * 4;
    int*   done   = (int*)p;      p += 1024;
    float* hring  = (float*)p;    // fallback uses slots 0,1; persist uses 0..3
    size_t pos_h  = (size_t)(p - (char*)d_ws);

    size_t persist_need = pos_h
        + 4LL * BATCH * HSZ * 4       // hring x4
        + 4LL * BATCH * HSZ * 2       // huring x4 (u32 = H/2 per row => B*256*4 bytes = B*H*2)
        + 2LL * BATCH * EMB * 4       // ering x2
        + 2LL * BATCH * 512 * 4;      // tmring x2
    size_t fb_need = pos_h
        + 2LL * BATCH * HSZ * 4 + (size_t)BATCH * HSZ * 2
        + (size_t)BATCH * EMB * 4 + (size_t)BATCH * 512 * 4;

    int nb = 0;
    hipError_t qerr = hipOccupancyMaxActiveBlocksPerMultiprocessor(
        &nb, reinterpret_cast<const void*>(persist_kernel), 256, 0);
    bool persist = (qerr == hipSuccess) && (nb >= 2) && (ws_size >= persist_need);

    unsigned* huring; float* ering; float* tmring;
    if (persist) {
        char* q = (char*)hring;
        q += 4LL * BATCH * HSZ * 4;
        huring = (unsigned*)q;  q += 4LL * BATCH * HSZ * 2;
        ering  = (float*)q;     q += 2LL * BATCH * EMB * 4;
        tmring = (float*)q;
    } else {
        char* q = (char*)hring;
        q += 2LL * BATCH * HSZ * 4;
        huring = (unsigned*)q;  q += (size_t)BATCH * HSZ * 2;
        ering  = (float*)q;     q += (size_t)BATCH * EMB * 4;
        tmring = (float*)q;
        if (ws_size < fb_need) return;   // cannot run at all (should not happen)
    }

    // prologue
    prep_kernel<<<1024, 256, 0, stream>>>(out_W, Wb, W_ih, W_hh, b_ih, b_hh,
                                          Wcat2, bcat2, done);
    gemm_atb<64, 64, 32, 4, 4><<<dim3(DFEAT / 64, BATCH / 64), 256, 0, stream>>>(
        x, enc_W, enc_b, feat, DFEAT, BATCH, DFEAT, DIN);
    gemm_atb<64, 64, 32, 4, 4><<<dim3(HSZ / 64, BATCH / 64), 256, 0, stream>>>(
        feat, in_W, in_b, hring, HSZ, BATCH, HSZ, DFEAT);   // h[0] -> slot 0

    if (persist) {
        int grid = nb * 256; if (grid > 1000) grid = 1000;
        persist_kernel<<<grid, 256, 0, stream>>>(
            hring, Wcat2, bcat2, ering, sos, huring, Wb,
            out_W, out_b, emb, seq, tmring, logits, done);
    } else {
        float* hc = hring;
        float* hn = hring + (size_t)BATCH * HSZ;
        for (int t = 0; t < SLEN; ++t) {
            float* lbase = logits + (long long)t * VOCAB;
            const float* lprev = logits + (long long)(t > 0 ? t - 1 : 0) * VOCAB;
            if (t == 0) {
                ag2_kernel<true><<<512, 256, 0, stream>>>(
                    hc, hn, Wcat2, bcat2, ering, sos, huring,
                    tmring, lprev, out_W, out_b, emb, seq, done, 0, 0);
            } else {
                ag2_kernel<false><<<512, 256, 0, stream>>>(
                    hc, hn, Wcat2, bcat2, ering, sos, huring,
                    tmring, lprev, out_W, out_b, emb, seq, done, 256 * t, t - 1);
            }
            logits_bm128_kernel<<<1000, 256, 0, stream>>>(
                (const ushort*)huring, Wb, out_b, lbase, tmring);
            float* tmp = hc; hc = hn; hn = tmp;
        }
        argmax_final<<<BATCH, 256, 0, stream>>>(
            tmring, logits + (long long)(SLEN - 1) * VOCAB, hc, out_W, out_b, seq, SLEN - 1);
    }
}

// Round 18
// 1119.019 us; speedup vs baseline: 1.0055x; 1.0055x over previous
//
#include <hip/hip_runtime.h>
#include <math.h>

#define BATCH 256
#define DIN 512
#define DFEAT 512
#define HSZ 512
#define VOCAB 32000
#define EMB 64
#define SLEN 16
#define NTILE 500          // VOCAB / 64 col-tiles (argmax view)
#define MARGIN 0.0625f

typedef __attribute__((ext_vector_type(8))) short bf16x8;
typedef __attribute__((ext_vector_type(4))) float f32x4;

__device__ inline unsigned bf16_rne(float x) {
    union { float f; unsigned u; } u; u.f = x;
    unsigned r = u.u + 0x7fff + ((u.u >> 16) & 1);
    return r >> 16;
}
__device__ inline void poll_ge(int* c, int target) {
    while (__hip_atomic_load(c, __ATOMIC_RELAXED, __HIP_MEMORY_SCOPE_AGENT) < target)
        __builtin_amdgcn_s_sleep(8);
}
__device__ inline void bump(int* c) {
    __hip_atomic_fetch_add(c, 1, __ATOMIC_RELEASE, __HIP_MEMORY_SCOPE_AGENT);
}
__device__ inline float alf(const float* p) {
    return __hip_atomic_load(p, __ATOMIC_RELAXED, __HIP_MEMORY_SCOPE_AGENT);
}
__device__ inline void asf(float* p, float v) {
    __hip_atomic_store(p, v, __ATOMIC_RELAXED, __HIP_MEMORY_SCOPE_AGENT);
}

// ---------- fp32 SMEM GEMM (prologue): C = A @ W^T (+bias) ----------
template<int BM, int BN, int BK, int TM, int TN>
__global__ __launch_bounds__(256) void gemm_atb(
    const float* __restrict__ A, const float* __restrict__ W,
    const float* __restrict__ bias, float* __restrict__ C, long long ldc,
    int M, int N, int K)
{
    __shared__ float As[BK][BM + 4];
    __shared__ float Bs[BK][BN + 4];
    constexpr int THREADS = (BM / TM) * (BN / TN);
    const int tid = threadIdx.x;
    const int tx = tid % (BN / TN);
    const int ty = tid / (BN / TN);
    const int row0 = blockIdx.y * BM;
    const int col0 = blockIdx.x * BN;
    float acc[TM][TN] = {};
    for (int k0 = 0; k0 < K; k0 += BK) {
        for (int i = tid; i < BM * BK; i += THREADS) {
            int m = i / BK, k = i % BK;
            As[k][m] = A[(long long)(row0 + m) * K + k0 + k];
        }
        for (int i = tid; i < BN * BK; i += THREADS) {
            int n = i / BK, k = i % BK;
            Bs[k][n] = W[(long long)(col0 + n) * K + k0 + k];
        }
        __syncthreads();
        #pragma unroll
        for (int kk = 0; kk < BK; ++kk) {
            float a[TM], b[TN];
            #pragma unroll
            for (int i = 0; i < TM; ++i) a[i] = As[kk][ty * TM + i];
            #pragma unroll
            for (int j = 0; j < TN; ++j) b[j] = Bs[kk][tx * TN + j];
            #pragma unroll
            for (int i = 0; i < TM; ++i)
                #pragma unroll
                for (int j = 0; j < TN; ++j)
                    acc[i][j] = fmaf(a[i], b[j], acc[i][j]);
        }
        __syncthreads();
    }
    #pragma unroll
    for (int i = 0; i < TM; ++i) {
        long long m = row0 + ty * TM + i;
        float* crow = C + m * ldc;
        #pragma unroll
        for (int j = 0; j < TN; ++j) {
            int n = col0 + tx * TN + j;
            float v = acc[i][j];
            if (bias) v += bias[n];
            crow[n] = v;
        }
    }
}

// ---------- prologue: Wb cast, Wcat2/bcat2 build, counter reset ----------
__global__ void prep_kernel(const float* __restrict__ out_W, ushort* __restrict__ Wb,
                            const float* __restrict__ W_ih, const float* __restrict__ W_hh,
                            const float* __restrict__ b_ih, const float* __restrict__ b_hh,
                            float* __restrict__ Wcat2, float* __restrict__ bcat2,
                            int* __restrict__ done)
{
    const int stride = gridDim.x * 256;
    const int t0 = blockIdx.x * 256 + threadIdx.x;
    for (int i = t0; i < VOCAB * HSZ / 4; i += stride) {
        const float4 v = ((const float4*)out_W)[i];
        ushort4 o;
        o.x = (ushort)bf16_rne(v.x); o.y = (ushort)bf16_rne(v.y);
        o.z = (ushort)bf16_rne(v.z); o.w = (ushort)bf16_rne(v.w);
        ((ushort4*)Wb)[i] = o;
    }
    for (long long i = t0; i < 2048LL * 576; i += stride) {
        int g = (int)(i / 576), k = (int)(i % 576);
        int j = g >> 2, comp = g & 3;
        float v;
        if (comp == 0)      v = (k < 64) ? W_ih[j * 64 + k]          : W_hh[(long long)j * 512 + k - 64];
        else if (comp == 1) v = (k < 64) ? W_ih[(512 + j) * 64 + k]  : W_hh[(long long)(512 + j) * 512 + k - 64];
        else if (comp == 2) v = (k < 64) ? W_ih[(1024 + j) * 64 + k] : 0.f;
        else                v = (k < 64) ? 0.f                        : W_hh[(long long)(1024 + j) * 512 + k - 64];
        Wcat2[i] = v;
    }
    for (int i = t0; i < 2048; i += stride) {
        int j = i >> 2, comp = i & 3;
        float bv = (comp == 0) ? b_ih[j] + b_hh[j]
                 : (comp == 1) ? b_ih[512 + j] + b_hh[512 + j]
                 : (comp == 2) ? b_ih[1024 + j] : b_hh[1024 + j];
        bcat2[i] = bv;
    }
    for (int i = t0; i < 256; i += stride) done[i] = 0;
}

// ================= shared G sub-bodies =================
// h-part: K=64..575, accumulates into acc[4]. Plain loads (inputs sealed by prev kernel).
__device__ __forceinline__ void gru_h_acc(int blk,
    const float* __restrict__ hprev, const float* __restrict__ Wcat2,
    float acc[4], char* sm)
{
    const int tid = threadIdx.x;
    const int ty = blk >> 5;
    const int tx = blk & 31;
    float* As = (float*)sm;
    float* Bs = (float*)(sm + 4608);
    const int tyt = tid >> 4;
    const int txt = tid & 15;
    for (int k0 = 64; k0 < 576; k0 += 64) {
        for (int i = tid; i < 16 * 64; i += 256) {
            int m = i >> 6, k = i & 63;
            As[k * 18 + m] = hprev[(long long)(ty * 16 + m) * 512 + (k0 - 64) + k];
        }
        for (int i = tid; i < 64 * 64; i += 256) {
            int n = i >> 6, k = i & 63;
            Bs[k * 68 + n] = Wcat2[(long long)(tx * 64 + n) * 576 + k0 + k];
        }
        __syncthreads();
        #pragma unroll 8
        for (int kk = 0; kk < 64; ++kk) {
            const float a = As[kk * 18 + tyt];
            const float4 b = *(const float4*)&Bs[kk * 68 + txt * 4];
            acc[0] = fmaf(a, b.x, acc[0]);
            acc[1] = fmaf(a, b.y, acc[1]);
            acc[2] = fmaf(a, b.z, acc[2]);
            acc[3] = fmaf(a, b.w, acc[3]);
        }
        __syncthreads();
    }
}

// e-part + gates + stores. useSos: t==0. coherentE: read ebuf via alf (same-kernel producer).
template<bool COHERENT_E>
__device__ __forceinline__ void gru_e_finish(int blk, bool useSos,
    const float* __restrict__ hprev, float* __restrict__ hnew,
    const float* __restrict__ Wcat2, const float* __restrict__ bcat2,
    const float* __restrict__ ebuf, const float* __restrict__ sos,
    unsigned* __restrict__ hbfu, float acc[4], char* sm)
{
    const int tid = threadIdx.x;
    const int ty = blk >> 5;
    const int tx = blk & 31;
    float* As = (float*)sm;
    float* Bs = (float*)(sm + 4608);
    const int tyt = tid >> 4;
    const int txt = tid & 15;
    {
        for (int i = tid; i < 16 * 64; i += 256) {
            int m = i >> 6, k = i & 63;
            float v;
            if (useSos) v = sos[k];
            else if (COHERENT_E) v = alf(&ebuf[(long long)(ty * 16 + m) * EMB + k]);
            else v = ebuf[(long long)(ty * 16 + m) * EMB + k];
            As[k * 18 + m] = v;
        }
        for (int i = tid; i < 64 * 64; i += 256) {
            int n = i >> 6, k = i & 63;
            Bs[k * 68 + n] = Wcat2[(long long)(tx * 64 + n) * 576 + k];
        }
        __syncthreads();
        #pragma unroll 8
        for (int kk = 0; kk < 64; ++kk) {
            const float a = As[kk * 18 + tyt];
            const float4 b = *(const float4*)&Bs[kk * 68 + txt * 4];
            acc[0] = fmaf(a, b.x, acc[0]);
            acc[1] = fmaf(a, b.y, acc[1]);
            acc[2] = fmaf(a, b.z, acc[2]);
            acc[3] = fmaf(a, b.w, acc[3]);
        }
        __syncthreads();
    }
    float* gt = (float*)sm;
    ushort* sh_hb = (ushort*)(sm + 8192);
    #pragma unroll
    for (int j = 0; j < 4; ++j)
        gt[tyt * 64 + txt * 4 + j] = acc[j];
    __syncthreads();
    {
        int row = tid >> 4, jl = tid & 15;
        int jg = tx * 16 + jl;
        float gr  = gt[row * 64 + jl * 4 + 0] + bcat2[jg * 4 + 0];
        float gz  = gt[row * 64 + jl * 4 + 1] + bcat2[jg * 4 + 1];
        float gni = gt[row * 64 + jl * 4 + 2] + bcat2[jg * 4 + 2];
        float gnh = gt[row * 64 + jl * 4 + 3] + bcat2[jg * 4 + 3];
        float r = 1.0f / (1.0f + expf(-gr));
        float z = 1.0f / (1.0f + expf(-gz));
        float n = tanhf(gni + r * gnh);
        long long bglob = ty * 16 + row;
        float hold = hprev[bglob * 512 + jg];
        float h = (1.0f - z) * n + z * hold;
        hnew[bglob * 512 + jg] = h;
        sh_hb[row * 16 + jl] = (ushort)bf16_rne(h);
    }
    __syncthreads();
    if (tid < 128) {
        int row = tid >> 3, jp = tid & 7;
        unsigned lo = sh_hb[row * 16 + jp * 2];
        unsigned hi = sh_hb[row * 16 + jp * 2 + 1];
        hbfu[(long long)(ty * 16 + row) * 256 + tx * 8 + jp] = (hi << 16) | lo;
    }
}

// ================= L body: fast loads (prev-kernel inputs); COHERENT_ST => sc1 stores + bump ====
template<bool COHERENT_ST>
__device__ __forceinline__ void logits_body_t(int bid, int t,
    const ushort* __restrict__ hbf, const ushort* __restrict__ Wb,
    const float* __restrict__ out_b, float* __restrict__ lbase,
    float* __restrict__ tmaxv, int* __restrict__ done, char* sm)
{
    char* As = sm;
    char* Bs = sm + 16384;
    float* s_mv = (float*)(sm + 24576);
    const int tid = threadIdx.x;
    const int lane = tid & 63;
    const int wave = tid >> 6;
    const int job = (bid & 7) * 125 + (bid >> 3);
    const int jx = job >> 1;
    const int jy = job & 1;
    const int row0 = jy * 128;
    const int col0 = jx * 64;

    f32x4 acc[2][4] = {};
    const int srow = tid >> 3;
    const int sch = tid & 7;

    for (int k0 = 0; k0 < 512; k0 += 64) {
        #pragma unroll
        for (int ra = 0; ra < 4; ++ra) {
            int row = ra * 32 + srow;
            const char* g = (const char*)(hbf + (long long)(row0 + row) * 512 + k0) + ((sch ^ (row & 7)) * 16);
            __builtin_amdgcn_global_load_lds(
                (const __attribute__((address_space(1))) void*)g,
                (__attribute__((address_space(3))) void*)(As + row * 128 + sch * 16), 16, 0, 0);
        }
        #pragma unroll
        for (int rb = 0; rb < 2; ++rb) {
            int row = rb * 32 + srow;
            const char* g = (const char*)(Wb + (long long)(col0 + row) * 512 + k0) + ((sch ^ (row & 7)) * 16);
            __builtin_amdgcn_global_load_lds(
                (const __attribute__((address_space(1))) void*)g,
                (__attribute__((address_space(3))) void*)(Bs + row * 128 + sch * 16), 16, 0, 0);
        }
        __syncthreads();
        #pragma unroll
        for (int k32 = 0; k32 < 64; k32 += 32) {
            bf16x8 af[2], bfr[4];
            #pragma unroll
            for (int f = 0; f < 2; ++f) {
                int rA = wave * 32 + f * 16 + (lane & 15);
                int byteA = (rA * 128 + (k32 + ((lane >> 4) << 3)) * 2) ^ ((rA & 7) << 4);
                af[f] = *(const bf16x8*)&As[byteA];
            }
            #pragma unroll
            for (int j = 0; j < 4; ++j) {
                int rB = j * 16 + (lane & 15);
                int byteB = (rB * 128 + (k32 + ((lane >> 4) << 3)) * 2) ^ ((rB & 7) << 4);
                bfr[j] = *(const bf16x8*)&Bs[byteB];
            }
            #pragma unroll
            for (int f = 0; f < 2; ++f)
                #pragma unroll
                for (int j = 0; j < 4; ++j)
                    acc[f][j] = __builtin_amdgcn_mfma_f32_16x16x32_bf16(af[f], bfr[j], acc[f][j], 0, 0, 0);
        }
        __syncthreads();
    }
    #pragma unroll
    for (int f = 0; f < 2; ++f) {
        #pragma unroll
        for (int q = 0; q < 4; ++q) {
            int r_local = wave * 32 + f * 16 + ((lane >> 4) << 2) + q;
            float* crow = lbase + (long long)(row0 + r_local) * (SLEN * (long long)VOCAB);
            float mv = -INFINITY;
            #pragma unroll
            for (int j = 0; j < 4; ++j) {
                int c = col0 + j * 16 + (lane & 15);
                float v = acc[f][j][q] + out_b[c];
                if (COHERENT_ST) asf(&crow[c], v);
                else __builtin_nontemporal_store(v, &crow[c]);
                mv = fmaxf(mv, v);
            }
            #pragma unroll
            for (int m = 1; m < 16; m <<= 1) mv = fmaxf(mv, __shfl_xor(mv, m, 64));
            if ((lane & 15) == 0) s_mv[r_local] = mv;
        }
    }
    __syncthreads();
    if (tid < 128) {
        if (COHERENT_ST) asf(&tmaxv[(long long)(row0 + tid) * 512 + jx], s_mv[tid]);
        else tmaxv[(long long)(row0 + tid) * 512 + jx] = s_mv[tid];
    }
    if (COHERENT_ST) {
        __syncthreads();
        if (tid == 0) bump(done + t * 8 + 1 + jy);
    }
}

// ================= A body: COHERENT reads of same-kernel tmaxv/logits =================
template<bool COHERENT>
__device__ __forceinline__ int argmax_body_t(int b, int tprev,
    const float* __restrict__ tmaxv, const float* __restrict__ lprev,
    const float* __restrict__ href, const float* __restrict__ out_W,
    const float* __restrict__ out_b, float* __restrict__ seq, char* sm)
{
    float* s_red = (float*)sm;
    int*   s_qt  = (int*)(sm + 1024);
    int*   s_cand= (int*)(sm + 1280);
    float* s_rv  = (float*)(sm + 1536);
    int*   s_cnt = (int*)(sm + 1792);
    int*   s_sym = (int*)(sm + 1800);
    const int tid = threadIdx.x;
    const int lane = tid & 63, wave = tid >> 6;
    const float* row = lprev + (long long)b * (SLEN * (long long)VOCAB);

    float v0 = COHERENT ? alf(&tmaxv[(long long)b * 512 + tid]) : tmaxv[(long long)b * 512 + tid];
    float v1 = (tid + 256 < NTILE)
        ? (COHERENT ? alf(&tmaxv[(long long)b * 512 + 256 + tid]) : tmaxv[(long long)b * 512 + 256 + tid])
        : -INFINITY;
    s_red[tid] = fmaxf(v0, v1); __syncthreads();
    for (int s = 128; s > 0; s >>= 1) {
        if (tid < s) s_red[tid] = fmaxf(s_red[tid], s_red[tid + s]);
        __syncthreads();
    }
    float M = s_red[0];
    if (tid == 0) { s_cnt[0] = 0; s_cnt[1] = 0; }
    __syncthreads();
    if (v0 >= M - MARGIN) { int s = atomicAdd(&s_cnt[0], 1); if (s < 64) s_qt[s] = tid; }
    if (v1 >= M - MARGIN) { int s = atomicAdd(&s_cnt[0], 1); if (s < 64) s_qt[s] = tid + 256; }
    __syncthreads();
    int nq = min(s_cnt[0], 64);
    for (int idx = tid; idx < nq * 64; idx += 256) {
        int c = s_qt[idx >> 6] * 64 + (idx & 63);
        float lv = COHERENT ? alf(&row[c]) : row[c];
        if (lv >= M - MARGIN) {
            int s = atomicAdd(&s_cnt[1], 1);
            if (s < 64) s_cand[s] = c;
        }
    }
    __syncthreads();
    int nc = min(s_cnt[1], 64);
    const float* hrow = href + (long long)b * 512;
    for (int ci = wave; ci < nc; ci += 4) {
        int vv = s_cand[ci];
        const float* wrow = out_W + (long long)vv * 512;
        float s = 0.f;
        for (int k = lane; k < 512; k += 64) s = fmaf(hrow[k], wrow[k], s);
        for (int off = 32; off > 0; off >>= 1) s += __shfl_down(s, off, 64);
        if (lane == 0) s_rv[ci] = s + out_b[vv];
    }
    __syncthreads();
    if (tid == 0) {
        float bv = -INFINITY; int sym = 0x7fffffff;
        for (int ci = 0; ci < nc; ++ci) {
            float xx = s_rv[ci]; int c = s_cand[ci];
            if (xx > bv || (xx == bv && c < sym)) { bv = xx; sym = c; }
        }
        if (sym < 0 || sym >= VOCAB) sym = 0;
        seq[b * SLEN + tprev] = (float)sym;
        *s_sym = sym;
    }
    __syncthreads();
    return *s_sym;
}

// ================= pipelined step kernel: K(t) = [L(t-1) || G(t)-h] -> A(t-1) -> G(t)-e ==========
__global__ __launch_bounds__(256) void step_kernel(
    int t, int hasL, int hasG, int hasA,
    const float* __restrict__ hprev, float* __restrict__ hnew,
    const float* __restrict__ Wcat2, const float* __restrict__ bcat2,
    float* __restrict__ ebuf, const float* __restrict__ sos,
    const unsigned* __restrict__ hbf_prev, unsigned* __restrict__ hbf_new,
    const ushort* __restrict__ Wb,
    const float* __restrict__ out_W, const float* __restrict__ out_b,
    const float* __restrict__ emb, float* __restrict__ seq,
    float* __restrict__ tmaxv, float* __restrict__ lprev,
    int* __restrict__ done)
{
    __shared__ __align__(16) char smem[25600];
    const int tid = threadIdx.x;
    const int bid = blockIdx.x;
    const bool isG = hasG && bid >= 256 && bid < 768;
    float acc[4] = {};

    // G-h: no dependencies (inputs from previous kernel) — overlaps L below at CU level
    if (isG) gru_h_acc(bid - 256, hprev, Wcat2, acc, smem);

    // L(t-1): all 1000 blocks; inputs from previous kernel (fast paths); coherent stores
    if (hasL)
        logits_body_t<true>(bid, t, (const ushort*)hbf_prev, Wb, out_b, lprev, tmaxv, done, smem);

    // A(t-1): blocks 0..255, after all L tiles of the row half
    if (hasA && bid < BATCH) {
        if (tid == 0) poll_ge(done + t * 8 + 1 + (bid >= 128 ? 1 : 0), 500);
        __syncthreads();
        int sym = argmax_body_t<true>(bid, t - 1, tmaxv, lprev, hprev, out_W, out_b, seq, smem);
        if (hasG) {
            if (tid < EMB)
                asf(&ebuf[(long long)bid * EMB + tid], emb[(long long)sym * EMB + tid]);
            __syncthreads();
            if (tid == 0) bump(done + t * 8);
        }
    }

    // G-e: wait for all A, then finish gates
    if (isG) {
        if (hasA) {
            if (tid == 0) poll_ge(done + t * 8, 256);
            __syncthreads();
        }
        gru_e_finish<true>(bid - 256, t == 0, hprev, hnew, Wcat2, bcat2,
                           ebuf, sos, hbf_new, acc, smem);
    }
}

// ================= fallback kernels (R14/R16-validated two-node path) =================
template<bool FIRST>
__global__ __launch_bounds__(256) void ag2_kernel(
    const float* __restrict__ hprev, float* __restrict__ hnew,
    const float* __restrict__ Wcat2, const float* __restrict__ bcat2,
    float* __restrict__ ebuf, const float* __restrict__ sos,
    unsigned* __restrict__ hbfu,
    const float* __restrict__ tmaxv, const float* __restrict__ lprev,
    const float* __restrict__ out_W, const float* __restrict__ out_b,
    const float* __restrict__ emb, float* __restrict__ seq,
    int* __restrict__ done, int wt_e, int tprev)
{
    __shared__ __align__(16) char smem[25600];
    const int tid = threadIdx.x;
    const int bid = blockIdx.x;
    if (!FIRST && bid < BATCH) {
        int sym = argmax_body_t<false>(bid, tprev, tmaxv, lprev, hprev, out_W, out_b, seq, smem);
        if (tid < EMB)
            asf(&ebuf[(long long)bid * EMB + tid], emb[(long long)sym * EMB + tid]);
        __syncthreads();
        if (tid == 0) bump(done);
        __syncthreads();
    }
    float acc[4] = {};
    gru_h_acc(bid, hprev, Wcat2, acc, smem);
    if (!FIRST) {
        if (tid == 0) poll_ge(done, wt_e);
        __syncthreads();
    }
    gru_e_finish<false>(bid, FIRST, hprev, hnew, Wcat2, bcat2, ebuf, sos, hbfu, acc, smem);
}

__global__ __launch_bounds__(256) void logits_bm128_kernel(
    const ushort* __restrict__ hbf, const ushort* __restrict__ Wb,
    const float* __restrict__ out_b,
    float* __restrict__ lbase, float* __restrict__ tmaxv)
{
    __shared__ __align__(16) char smem[25600];
    logits_body_t<false>(blockIdx.x, 0, hbf, Wb, out_b, lbase, tmaxv, nullptr, smem);
}

__global__ __launch_bounds__(256) void argmax_final(
    const float* __restrict__ tmaxv, const float* __restrict__ lbase,
    const float* __restrict__ h, const float* __restrict__ out_W,
    const float* __restrict__ out_b, float* __restrict__ seq, int t)
{
    __shared__ __align__(16) char smem[2048];
    argmax_body_t<false>(blockIdx.x, t, tmaxv, lbase, h, out_W, out_b, seq, smem);
}

extern "C" void kernel_launch(void* const* d_in, const int* in_sizes, int n_in,
                              void* d_out, int out_size, void* d_ws, size_t ws_size,
                              hipStream_t stream) {
    const float* x     = (const float*)d_in[0];
    const float* enc_W = (const float*)d_in[1];
    const float* enc_b = (const float*)d_in[2];
    const float* in_W  = (const float*)d_in[3];
    const float* in_b  = (const float*)d_in[4];
    const float* W_ih  = (const float*)d_in[5];
    const float* W_hh  = (const float*)d_in[6];
    const float* b_ih  = (const float*)d_in[7];
    const float* b_hh  = (const float*)d_in[8];
    const float* out_W = (const float*)d_in[9];
    const float* out_b = (const float*)d_in[10];
    const float* emb   = (const float*)d_in[11];
    const float* sos   = (const float*)d_in[12];

    float* seq    = (float*)d_out;
    float* logits = (float*)d_out + BATCH * SLEN;

    char* p = (char*)d_ws;
    ushort* Wb    = (ushort*)p;   p += (size_t)VOCAB * HSZ * 2;
    float* Wcat2  = (float*)p;    p += (size_t)2048 * 576 * 4;
    float* bcat2  = (float*)p;    p += 2048 * 4;
    float* feat   = (float*)p;    p += (size_t)BATCH * DFEAT * 4;
    int*   done   = (int*)p;      p += 1024;
    float* hs0    = (float*)p;    p += (size_t)BATCH * HSZ * 4;
    float* hs1    = (float*)p;    p += (size_t)BATCH * HSZ * 4;
    unsigned* hu0 = (unsigned*)p; p += (size_t)BATCH * HSZ * 2;
    unsigned* hu1 = (unsigned*)p; p += (size_t)BATCH * HSZ * 2;
    float* ebuf   = (float*)p;    p += (size_t)BATCH * EMB * 4;
    float* tmaxv  = (float*)p;    p += (size_t)BATCH * 512 * 4;

    int nb = 0;
    hipError_t qerr = hipOccupancyMaxActiveBlocksPerMultiprocessor(
        &nb, reinterpret_cast<const void*>(step_kernel), 256, 0);
    bool pipelined = (qerr == hipSuccess) && (nb >= 4);   // 1000 <= nb*256

    // prologue
    prep_kernel<<<1024, 256, 0, stream>>>(out_W, Wb, W_ih, W_hh, b_ih, b_hh,
                                          Wcat2, bcat2, done);
    gemm_atb<64, 64, 32, 4, 4><<<dim3(DFEAT / 64, BATCH / 64), 256, 0, stream>>>(
        x, enc_W, enc_b, feat, DFEAT, BATCH, DFEAT, DIN);
    gemm_atb<64, 64, 32, 4, 4><<<dim3(HSZ / 64, BATCH / 64), 256, 0, stream>>>(
        feat, in_W, in_b, hs0, HSZ, BATCH, HSZ, DFEAT);   // h(0) -> slot 0

    if (pipelined) {
        // K(t) for t = 0..16:  L(t-1) || G(t)-h  ->  A(t-1)  ->  G(t)-e
        for (int t = 0; t <= SLEN; ++t) {
            float* hprev = (t & 1) ? hs1 : hs0;
            float* hnew  = (t & 1) ? hs0 : hs1;
            unsigned* hbf_new  = (t & 1) ? hu1 : hu0;
            unsigned* hbf_prev = (t & 1) ? hu0 : hu1;   // (t-1)&1 parity
            float* lprev = logits + (long long)(t > 0 ? t - 1 : 0) * VOCAB;
            int hasL = (t >= 1), hasG = (t < SLEN), hasA = (t >= 1);
            step_kernel<<<1000, 256, 0, stream>>>(
                t, hasL, hasG, hasA, hprev, hnew, Wcat2, bcat2, ebuf, sos,
                hbf_prev, hbf_new, Wb, out_W, out_b, emb, seq, tmaxv, lprev, done);
        }
    } else {
        float* hc = hs0;
        float* hn = hs1;
        for (int t = 0; t < SLEN; ++t) {
            float* lbase = logits + (long long)t * VOCAB;
            const float* lprev = logits + (long long)(t > 0 ? t - 1 : 0) * VOCAB;
            if (t == 0) {
                ag2_kernel<true><<<512, 256, 0, stream>>>(
                    hc, hn, Wcat2, bcat2, ebuf, sos, hu0,
                    tmaxv, lprev, out_W, out_b, emb, seq, done, 0, 0);
            } else {
                ag2_kernel<false><<<512, 256, 0, stream>>>(
                    hc, hn, Wcat2, bcat2, ebuf, sos, hu0,
                    tmaxv, lprev, out_W, out_b, emb, seq, done, 256 * t, t - 1);
            }
            logits_bm128_kernel<<<1000, 256, 0, stream>>>(
                (const ushort*)hu0, Wb, out_b, lbase, tmaxv);
            float* tmp = hc; hc = hn; hn = tmp;
        }
        argmax_final<<<BATCH, 256, 0, stream>>>(
            tmaxv, logits + (long long)(SLEN - 1) * VOCAB, hc, out_W, out_b, seq, SLEN - 1);
    }
}